// Round 2
// baseline (197.401 us; speedup 1.0000x reference)
//
#include <hip/hip_runtime.h>
#include <hip/hip_fp16.h>
#include <cmath>

// Problem constants: (N,C,H,W) = (16,3,512,512), fp32
#define PLANE (512*512)          // 262144
#define NPLANES 48               // N*C
#define NEL (48*PLANE)           // 12582912

struct Taps { float k[9]; };
struct CMat { float w[3][3]; };   // C-axis 9-tap blur collapsed to 3x3 matrix

// ws layout (uint = packed (E,G) __half2, TILED):
//   idx(q, h, w) = ((h*8 + (w>>6))*48 + q)*64 + (w&63)     q = plane 0..47
//   wsS[0 .. NEL) : HW-blurred log pairs (E in lo half, G in hi half)
//   wsI[0 .. NEL) : (I + 1e-6) pairs, same order
// Total 2*NEL uints = 100.7 MB.  k_cn_loss touches ONLY ws (L2/L3-warm).

#define FOLD(r) ((r) < 0 ? (-1 - (r)) : ((r) > 511 ? (1023 - (r)) : (r)))

// ---------------------------------------------------------------------------
// Kernel 1: fused log + W-blur + H-blur + I staging for BOTH images at once.
// ONE wave per (8-row strip x full 512-col row) of one (E,G) plane pair:
// 8 cols/lane -> NO interior halo (no halo loads, no halo logs, no interior
// cndmasks, no barriers). Window via 8 shuffles/row; image-edge reflection
// from own registers. W-blur runs in packed (E,G) fp16 (72 pk-fma/row for
// both images). grid (64, 48), block 64.
// ---------------------------------------------------------------------------
__global__ __launch_bounds__(64, 3)
void k_blur_hw(const float* __restrict__ inE, const float* __restrict__ inG,
               uint* __restrict__ wsS, uint* __restrict__ wsI, Taps tp)
{
    const int l  = threadIdx.x;               // 0..63 -> cols 8l..8l+7
    const int r0 = blockIdx.x * 8;            // 64 rowgroups
    const int z  = blockIdx.y;                // plane pair 0..47
    const float* __restrict__ srcE = inE + z * PLANE;
    const float* __restrict__ srcG = inG + z * PLANE;
    const int col   = 8 * l;
    const int tile  = l >> 3;                 // w-tile 0..7
    const int inner = col & 63;

    __half2 kh[9];
#pragma unroll
    for (int t = 0; t < 9; ++t) kh[t] = __float2half2_rn(tp.k[t]);

    __half2 ring[9][8];                       // W-blurred rows, (E,G) per col

    // depth-2 load pipeline (rows r0-4+j)
    float4 eA[2], eB[2], gA[2], gB[2];
#pragma unroll
    for (int s = 0; s < 2; ++s) {
        const int row = FOLD(r0 - 4 + s);
        eA[s] = *(const float4*)(srcE + row * 512 + col);
        eB[s] = *(const float4*)(srcE + row * 512 + col + 4);
        gA[s] = *(const float4*)(srcG + row * 512 + col);
        gB[s] = *(const float4*)(srcG + row * 512 + col + 4);
    }

#pragma unroll
    for (int j = 0; j < 16; ++j) {            // input row r0-4+j
        const float4 ea = eA[0], eb = eB[0], ga = gA[0], gb = gB[0];
        eA[0] = eA[1]; eB[0] = eB[1]; gA[0] = gA[1]; gB[0] = gB[1];
        if (j + 2 < 16) {                     // prefetch row j+2
            const int row = FOLD(r0 - 2 + j);
            eA[1] = *(const float4*)(srcE + row * 512 + col);
            eB[1] = *(const float4*)(srcE + row * 512 + col + 4);
            gA[1] = *(const float4*)(srcG + row * 512 + col);
            gB[1] = *(const float4*)(srcG + row * 512 + col + 4);
        }

        // stage (I+eps) pairs for the 8 center rows
        if (j >= 4 && j < 12) {
            const int ri = r0 + j - 4;
            __half2 i0 = __floats2half2_rn(ea.x + 1e-6f, ga.x + 1e-6f);
            __half2 i1 = __floats2half2_rn(ea.y + 1e-6f, ga.y + 1e-6f);
            __half2 i2 = __floats2half2_rn(ea.z + 1e-6f, ga.z + 1e-6f);
            __half2 i3 = __floats2half2_rn(ea.w + 1e-6f, ga.w + 1e-6f);
            __half2 i4 = __floats2half2_rn(eb.x + 1e-6f, gb.x + 1e-6f);
            __half2 i5 = __floats2half2_rn(eb.y + 1e-6f, gb.y + 1e-6f);
            __half2 i6 = __floats2half2_rn(eb.z + 1e-6f, gb.z + 1e-6f);
            __half2 i7 = __floats2half2_rn(eb.w + 1e-6f, gb.w + 1e-6f);
            uint* dp = wsI + (((ri * 8 + tile) * 48) + z) * 64 + inner;
            *(uint4*)(dp)     = make_uint4(*(uint*)&i0, *(uint*)&i1,
                                           *(uint*)&i2, *(uint*)&i3);
            *(uint4*)(dp + 4) = make_uint4(*(uint*)&i4, *(uint*)&i5,
                                           *(uint*)&i6, *(uint*)&i7);
        }

        // fp32 log -> packed (E,G) fp16
        __half2 c[8];
        c[0] = __floats2half2_rn(__logf(ea.x + 1e-6f), __logf(ga.x + 1e-6f));
        c[1] = __floats2half2_rn(__logf(ea.y + 1e-6f), __logf(ga.y + 1e-6f));
        c[2] = __floats2half2_rn(__logf(ea.z + 1e-6f), __logf(ga.z + 1e-6f));
        c[3] = __floats2half2_rn(__logf(ea.w + 1e-6f), __logf(ga.w + 1e-6f));
        c[4] = __floats2half2_rn(__logf(eb.x + 1e-6f), __logf(gb.x + 1e-6f));
        c[5] = __floats2half2_rn(__logf(eb.y + 1e-6f), __logf(gb.y + 1e-6f));
        c[6] = __floats2half2_rn(__logf(eb.z + 1e-6f), __logf(gb.z + 1e-6f));
        c[7] = __floats2half2_rn(__logf(eb.w + 1e-6f), __logf(gb.w + 1e-6f));

        // 16-wide window: 4 from up-neighbor, own 8, 4 from down-neighbor
        __half2 win[16];
#pragma unroll
        for (int i = 0; i < 4; ++i) {
            int v = __shfl_up(*(const int*)&c[4 + i], 1);
            win[i] = *(__half2*)&v;
        }
#pragma unroll
        for (int i = 0; i < 8; ++i) win[4 + i] = c[i];
#pragma unroll
        for (int i = 0; i < 4; ++i) {
            int v = __shfl_down(*(const int*)&c[i], 1);
            win[12 + i] = *(__half2*)&v;
        }
        if (l == 0) {                         // cols -4..-1 -> 3,2,1,0
            win[0] = c[3]; win[1] = c[2]; win[2] = c[1]; win[3] = c[0];
        }
        if (l == 63) {                        // cols 512..515 -> 511..508
            win[12] = c[7]; win[13] = c[6]; win[14] = c[5]; win[15] = c[4];
        }

        // W-blur, packed (E,G) fp16
#pragma unroll
        for (int i = 0; i < 8; ++i) {
            __half2 a = __hmul2(kh[0], win[i]);
#pragma unroll
            for (int t = 1; t < 9; ++t) a = __hfma2(kh[t], win[i + t], a);
            ring[j % 9][i] = a;
        }

        // H-blur + store once 9 rows live (output row r0+j-8)
        if (j >= 8) {
            __half2 a[8];
#pragma unroll
            for (int i = 0; i < 8; ++i) a[i] = __hmul2(kh[0], ring[(j - 8) % 9][i]);
#pragma unroll
            for (int t = 1; t < 9; ++t)
#pragma unroll
                for (int i = 0; i < 8; ++i)
                    a[i] = __hfma2(kh[t], ring[(j - 8 + t) % 9][i], a[i]);
            const int ro = r0 + j - 8;
            uint* dp = wsS + (((ro * 8 + tile) * 48) + z) * 64 + inner;
            *(uint4*)(dp)     = make_uint4(*(uint*)&a[0], *(uint*)&a[1],
                                           *(uint*)&a[2], *(uint*)&a[3]);
            *(uint4*)(dp + 4) = make_uint4(*(uint*)&a[4], *(uint*)&a[5],
                                           *(uint*)&a[6], *(uint*)&a[7]);
        }
    }
}

// ---------------------------------------------------------------------------
// Kernel 2: C-blur + N-blur + loss. ONE (h,w) point per thread; the half2
// lanes carry (E,G) of that point, so every pk-fma serves both images.
// grid (1024), block (256).  (unchanged from the passing version)
// ---------------------------------------------------------------------------
__global__ __launch_bounds__(256)
void k_cn_loss(const uint* __restrict__ wsS, const uint* __restrict__ wsI,
               float* __restrict__ out, Taps tp, CMat cm)
{
    const int tid = threadIdx.x;
    const int p   = blockIdx.x * 256 + tid;      // point index 0..262143
    const int w   = p & 511;
    const int h   = p >> 9;
    const int base = ((h * 8 + (w >> 6)) * 48) * 64 + (w & 63);
    const uint* __restrict__ sb = wsS + base;
    const uint* __restrict__ ib = wsI + base;
    // plane q at +q*64

    __half2 k2[9], cw[3][3];
#pragma unroll
    for (int t = 0; t < 9; ++t) k2[t] = __float2half2_rn(tp.k[t]);
#pragma unroll
    for (int i = 0; i < 3; ++i)
#pragma unroll
        for (int jj = 0; jj < 3; ++jj) cw[i][jj] = __float2half2_rn(cm.w[i][jj]);

    __half2 r[9][3];                             // C-blurred (E,G), slot = m % 9

#define LOADS(m, u)                                                            \
    u[0] = sb[((m) * 3 + 0) * 64];                                             \
    u[1] = sb[((m) * 3 + 1) * 64];                                             \
    u[2] = sb[((m) * 3 + 2) * 64];

#define CBLUR(u, d)                                                            \
    {                                                                          \
        __half2 v0 = *(__half2*)&u[0];                                         \
        __half2 v1 = *(__half2*)&u[1];                                         \
        __half2 v2 = *(__half2*)&u[2];                                         \
        d[0] = __hfma2(cw[0][0], v0, __hfma2(cw[0][1], v1, __hmul2(cw[0][2], v2))); \
        d[1] = __hfma2(cw[1][0], v0, __hfma2(cw[1][1], v1, __hmul2(cw[1][2], v2))); \
        d[2] = __hfma2(cw[2][0], v0, __hfma2(cw[2][1], v1, __hmul2(cw[2][2], v2))); \
    }

    {
        uint su[3];
#pragma unroll
        for (int m = 0; m < 4; ++m) { LOADS(m, su); CBLUR(su, r[m]); }
    }
    uint nu[3];
    LOADS(4, nu);
    uint iu[3];
    iu[0] = ib[0]; iu[1] = ib[64]; iu[2] = ib[128];

    float acc = 0.f;
#pragma unroll
    for (int n = 0; n < 16; ++n) {
        uint niu[3];
        if (n + 1 < 16) {
#pragma unroll
            for (int c = 0; c < 3; ++c) niu[c] = ib[((n + 1) * 3 + c) * 64];
        }
        const int mnew = n + 4;
        if (mnew < 16) {
            CBLUR(nu, r[mnew % 9]);
            if (mnew + 1 < 16) { LOADS(mnew + 1, nu); }
        }
#pragma unroll
        for (int c = 0; c < 3; ++c) {
            __half2 s2 = __float2half2_rn(0.f);
#pragma unroll
            for (int t = 0; t < 9; ++t) {
                int m = n - 4 + t;
                m = (m < 0) ? (-1 - m) : ((m > 15) ? (31 - m) : m);  // compile-time
                s2 = __hfma2(k2[t], r[m % 9][c], s2);
            }
            const float2 sf  = __half22float2(s2);
            const float2 if2 = __half22float2(*(__half2*)&iu[c]);

            float eE = __expf(-sf.x), eG = __expf(-sf.y);
            float Re = if2.x * eE;
            float Rg = if2.y * eG;
            float Le = __builtin_amdgcn_rcpf(eE);
            float Lg = __builtin_amdgcn_rcpf(eG);
            float dr = Re - Rg, dl = Le - Lg;
            acc += dr * dr + dl * dl;
        }
        if (n + 1 < 16) { iu[0] = niu[0]; iu[1] = niu[1]; iu[2] = niu[2]; }
    }
#undef LOADS
#undef CBLUR

    __shared__ float red[256];
    red[tid] = acc;
    __syncthreads();
#pragma unroll
    for (int s = 128; s > 0; s >>= 1) {
        if (tid < s) red[tid] += red[tid + s];
        __syncthreads();
    }
    if (tid == 0) atomicAdd(out, red[0] * (1.0f / (float)NEL));
}

extern "C" void kernel_launch(void* const* d_in, const int* in_sizes, int n_in,
                              void* d_out, int out_size, void* d_ws, size_t ws_size,
                              hipStream_t stream) {
    const float* Ie = (const float*)d_in[0];
    const float* Ig = (const float*)d_in[1];

    // Gaussian taps: sigma=1, radius=int(4*1+0.5)=4, double-precision normalize
    Taps tp;
    {
        double kk[9], s = 0.0;
        for (int i = 0; i < 9; ++i) { double x = (double)(i - 4); kk[i] = exp(-0.5 * x * x); s += kk[i]; }
        for (int i = 0; i < 9; ++i) tp.k[i] = (float)(kk[i] / s);
    }

    // C-axis (size 3) 9-tap symmetric blur collapsed to a 3x3 matrix
    CMat cm;
    {
        for (int c = 0; c < 3; ++c) {
            cm.w[c][0] = cm.w[c][1] = cm.w[c][2] = 0.f;
            for (int t = 0; t < 9; ++t) {
                int m = c - 4 + t;
                int mm = ((m % 6) + 6) % 6;          // symmetric reflect, period 6
                if (mm > 2) mm = 5 - mm;
                cm.w[c][mm] += tp.k[t];
            }
        }
    }

    uint* wsS = (uint*)d_ws;                     // packed (E,G) blurred logs
    uint* wsI = wsS + (size_t)NEL;               // packed (E,G) (I+eps)

    hipMemsetAsync(d_out, 0, sizeof(float), stream);  // zero the atomic target
    dim3 g1(64, 48);
    k_blur_hw<<<g1, 64, 0, stream>>>(Ie, Ig, wsS, wsI, tp);
    k_cn_loss<<<1024, 256, 0, stream>>>(wsS, wsI, (float*)d_out, tp, cm);
}

// Round 4
// 163.417 us; speedup vs baseline: 1.2080x; 1.2080x over previous
//
#include <hip/hip_runtime.h>
#include <hip/hip_fp16.h>
#include <cmath>

// Problem constants: (N,C,H,W) = (16,3,512,512), fp32
#define PLANE (512*512)          // 262144
#define NPLANES 48               // N*C
#define NEL (48*PLANE)           // 12582912

struct Taps { float k[9]; };
struct CMat { float w[3][3]; };   // C-axis 9-tap blur collapsed to 3x3 matrix

// ws layout (all fp16, TILED, round-0 compatible):
//   ushort index(p, h, w-slot) = ((h*8 + tile)*96 + p)*64 + slot
// Each lane owns 8 cols (col=8l..8l+7) stored as 4 uints pairing
// (col+i, col+i+4) in (lo,hi) halves. wsS and wsI use the SAME pairing, and
// k_cn_loss is pairing-agnostic (loss is an order-independent mean; C/N blurs
// act per-point across planes), so round-0 k_cn_loss works unchanged.
//   wsS[0 .. 2*NEL)   : HW-blurred log, planes 0..47 = image E, 48..95 = G
//   wsI[0 .. 2*NEL)   : (I + 1e-6) values, same plane order

#define FOLD(r) ((r) < 0 ? (-1 - (r)) : ((r) > 511 ? (1023 - (r)) : (r)))

// ---------------------------------------------------------------------------
// Kernel 1: fused log + W-blur + H-blur + I-fp16 staging.
// ONE wave per (16-row strip x FULL 512-col row) of one plane: 8 cols/lane,
// no interior halo (no halo loads/logs/cndmasks, no barriers). Depth-3 load
// pipeline (round-0 proven). Window via 8 packed shuffles + bit-merges;
// W-blur and H-blur both packed fp16 over (i,i+4) col pairs (36 pk-fma each).
// grid (32, 96), block 64 -> 3072 waves = 12/CU, amp 24/16 = 1.5.
// ---------------------------------------------------------------------------
__global__ __launch_bounds__(64)
void k_blur_hw(const float* __restrict__ inE, const float* __restrict__ inG,
               ushort* __restrict__ wsS, ushort* __restrict__ wsI, Taps tp)
{
    const int l  = threadIdx.x;               // 0..63 -> cols 8l..8l+7
    const int r0 = blockIdx.x * 16;           // 32 rowgroups
    const int z  = blockIdx.y;                // plane 0..95
    const float* __restrict__ src = (z < NPLANES) ? (inE + z * PLANE)
                                                  : (inG + (z - NPLANES) * PLANE);
    const int col  = 8 * l;
    const int tile = l >> 3;                  // w-tile 0..7
    const int sh   = (l & 7) * 8;             // ushort offset inside tile block

    __half2 kh[9];
#pragma unroll
    for (int t = 0; t < 9; ++t) kh[t] = __float2half2_rn(tp.k[t]);

    uint ring[12][4];                         // W-blurred rows, (i,i+4) pairs

    // depth-3 load pipeline over rows r0-4+j
    float4 pA[3], pB[3];
#pragma unroll
    for (int s = 0; s < 3; ++s) {
        const int row = FOLD(r0 - 4 + s);
        pA[s] = *(const float4*)(src + row * 512 + col);
        pB[s] = *(const float4*)(src + row * 512 + col + 4);
    }

    for (int jb = 0; jb < 24; jb += 12) {
#pragma unroll
        for (int u = 0; u < 12; ++u) {
            const int j = jb + u;             // input row r0-4+j

            const float4 a = pA[0], b = pB[0];
            pA[0] = pA[1]; pA[1] = pA[2];
            pB[0] = pB[1]; pB[1] = pB[2];
            if (j + 3 < 24) {                 // load row j+3 (3-iter slack)
                const int row = FOLD(r0 - 1 + j);
                pA[2] = *(const float4*)(src + row * 512 + col);
                pB[2] = *(const float4*)(src + row * 512 + col + 4);
            }

            const float a0 = a.x + 1e-6f, a1 = a.y + 1e-6f;
            const float a2 = a.z + 1e-6f, a3 = a.w + 1e-6f;
            const float b0 = b.x + 1e-6f, b1 = b.y + 1e-6f;
            const float b2 = b.z + 1e-6f, b3 = b.w + 1e-6f;

            // stage (I+eps) as fp16 pairs for the 16 center rows
            if (j >= 4 && j < 20) {
                const int ri = r0 + j - 4;
                __half2 i0 = __floats2half2_rn(a0, b0);
                __half2 i1 = __floats2half2_rn(a1, b1);
                __half2 i2 = __floats2half2_rn(a2, b2);
                __half2 i3 = __floats2half2_rn(a3, b3);
                ushort* dpI = wsI + (((ri * 8 + tile) * 96) + z) * 64 + sh;
                *(uint4*)dpI = make_uint4(*(uint*)&i0, *(uint*)&i1,
                                          *(uint*)&i2, *(uint*)&i3);
            }

            // fp32 log -> packed (i,i+4) fp16 pairs
            uint c[4];
            {
                __half2 h0 = __floats2half2_rn(__logf(a0), __logf(b0));
                __half2 h1 = __floats2half2_rn(__logf(a1), __logf(b1));
                __half2 h2 = __floats2half2_rn(__logf(a2), __logf(b2));
                __half2 h3 = __floats2half2_rn(__logf(a3), __logf(b3));
                c[0] = *(uint*)&h0; c[1] = *(uint*)&h1;
                c[2] = *(uint*)&h2; c[3] = *(uint*)&h3;
            }

            // 12 packed windows: wpk[x] = (w[col-4+x], w[col+x]), x=0..11
            uint wpk[12];
#pragma unroll
            for (int i = 0; i < 4; ++i) {
                const uint up = (uint)__shfl_up((int)c[i], 1);
                const uint dn = (uint)__shfl_down((int)c[i], 1);
                wpk[i]     = (up >> 16) | (c[i] << 16);   // (up.hi, own.lo)
                wpk[4 + i] = c[i];
                wpk[8 + i] = (c[i] >> 16) | (dn << 16);   // (own.hi, down.lo)
            }
            if (l == 0) {                     // reflect cols -4..-1 -> 3..0
#pragma unroll
                for (int x = 0; x < 4; ++x)
                    wpk[x] = (c[3 - x] & 0xffffu) | (c[x] << 16);
            }
            if (l == 63) {                    // reflect cols 512..515 -> 511..508
                wpk[8]  = (c[0] >> 16) | (c[3] & 0xffff0000u);
                wpk[9]  = (c[1] >> 16) | (c[2] & 0xffff0000u);
                wpk[10] = (c[2] >> 16) | (c[1] & 0xffff0000u);
                wpk[11] = (c[3] >> 16) | (c[0] & 0xffff0000u);
            }

            // W-blur, packed fp16: out_pk[i] = (out[col+i], out[col+i+4])
#pragma unroll
            for (int i = 0; i < 4; ++i) {
                __half2 acc = __hmul2(kh[0], *(__half2*)&wpk[i]);
#pragma unroll
                for (int t = 1; t < 9; ++t)
                    acc = __hfma2(kh[t], *(__half2*)&wpk[i + t], acc);
                ring[u][i] = *(uint*)&acc;
            }

            // H-blur + store once 9 rows live (output row r0+j-8)
            if (j >= 8) {
                __half2 s0, s1, s2, s3;
                {
                    const int sl = (u + 4) % 12;          // slot of row j-8
                    s0 = __hmul2(kh[0], *(__half2*)&ring[sl][0]);
                    s1 = __hmul2(kh[0], *(__half2*)&ring[sl][1]);
                    s2 = __hmul2(kh[0], *(__half2*)&ring[sl][2]);
                    s3 = __hmul2(kh[0], *(__half2*)&ring[sl][3]);
                }
#pragma unroll
                for (int t = 1; t < 9; ++t) {
                    const int sl = (u + 4 + t) % 12;      // compile-time
                    s0 = __hfma2(kh[t], *(__half2*)&ring[sl][0], s0);
                    s1 = __hfma2(kh[t], *(__half2*)&ring[sl][1], s1);
                    s2 = __hfma2(kh[t], *(__half2*)&ring[sl][2], s2);
                    s3 = __hfma2(kh[t], *(__half2*)&ring[sl][3], s3);
                }
                const int ro = r0 + j - 8;
                ushort* dpS = wsS + (((ro * 8 + tile) * 96) + z) * 64 + sh;
                *(uint4*)dpS = make_uint4(*(uint*)&s0, *(uint*)&s1,
                                          *(uint*)&s2, *(uint*)&s3);
            }
        }
    }
}

// ---------------------------------------------------------------------------
// Kernel 2: C-blur + N-blur + loss. TWO (h,w) points per thread (one uint);
// ALL loads from the warm fp16 tiled ws (S and I+eps). Packed-half2 ring math.
// grid (512), block (256). (round-0 verified version, unchanged)
// ---------------------------------------------------------------------------
__global__ __launch_bounds__(256)
void k_cn_loss(const ushort* __restrict__ wsS, const ushort* __restrict__ wsI,
               float* __restrict__ out, Taps tp, CMat cm)
{
    const int tid = threadIdx.x;
    const int P   = blockIdx.x * 256 + tid;      // pair index
    const int hw0 = P * 2;                       // first slot (even)
    const int off = (hw0 >> 6) * (96 * 64) + (hw0 & 63);
    const ushort* sbase = wsS + off;
    const ushort* ibase = wsI + off;
    // E plane q: uint at +q*64; G plane q: +(48+q)*64

    __half2 k2[9], cw[3][3];
#pragma unroll
    for (int t = 0; t < 9; ++t) k2[t] = __float2half2_rn(tp.k[t]);
#pragma unroll
    for (int i = 0; i < 3; ++i)
#pragma unroll
        for (int j = 0; j < 3; ++j) cw[i][j] = __float2half2_rn(cm.w[i][j]);

    __half2 re[9][3];   // ring of C-blurred smoothed-log(E), slot = m % 9
    __half2 rg[9][3];

#define LOADRAW(m, uE, uG)                                                     \
    uE[0] = *(const uint*)(sbase + ((m) * 3 + 0) * 64);                        \
    uE[1] = *(const uint*)(sbase + ((m) * 3 + 1) * 64);                        \
    uE[2] = *(const uint*)(sbase + ((m) * 3 + 2) * 64);                        \
    uG[0] = *(const uint*)(sbase + (48 + (m) * 3 + 0) * 64);                   \
    uG[1] = *(const uint*)(sbase + (48 + (m) * 3 + 1) * 64);                   \
    uG[2] = *(const uint*)(sbase + (48 + (m) * 3 + 2) * 64);

#define CBLUR(u, dst)                                                          \
    {                                                                          \
        __half2 v0 = *(__half2*)&u[0];                                         \
        __half2 v1 = *(__half2*)&u[1];                                         \
        __half2 v2 = *(__half2*)&u[2];                                         \
        dst[0] = __hfma2(cw[0][0], v0, __hfma2(cw[0][1], v1, __hmul2(cw[0][2], v2))); \
        dst[1] = __hfma2(cw[1][0], v0, __hfma2(cw[1][1], v1, __hmul2(cw[1][2], v2))); \
        dst[2] = __hfma2(cw[2][0], v0, __hfma2(cw[2][1], v1, __hmul2(cw[2][2], v2))); \
    }

#pragma unroll
    for (int m = 0; m < 4; ++m) {
        uint uE[3], uG[3];
        LOADRAW(m, uE, uG);
        CBLUR(uE, re[m]); CBLUR(uG, rg[m]);
    }
    uint nuE[3], nuG[3];
    LOADRAW(4, nuE, nuG);
    uint ieq[3], igq[3];                         // packed (I+eps) pairs
#pragma unroll
    for (int c = 0; c < 3; ++c) {
        ieq[c] = *(const uint*)(ibase + c * 64);
        igq[c] = *(const uint*)(ibase + (48 + c) * 64);
    }

    float acc = 0.f;
#pragma unroll
    for (int n = 0; n < 16; ++n) {
        uint nie[3], nig[3];
        if (n + 1 < 16) {
#pragma unroll
            for (int c = 0; c < 3; ++c) {
                nie[c] = *(const uint*)(ibase + (((n + 1) * 3 + c)) * 64);
                nig[c] = *(const uint*)(ibase + ((48 + (n + 1) * 3 + c)) * 64);
            }
        }
        const int mnew = n + 4;
        if (mnew < 16) {
            CBLUR(nuE, re[mnew % 9]); CBLUR(nuG, rg[mnew % 9]);
            if (mnew + 1 < 16) { LOADRAW(mnew + 1, nuE, nuG); }
        }
#pragma unroll
        for (int c = 0; c < 3; ++c) {
            __half2 se2 = __float2half2_rn(0.f), sg2 = se2;
#pragma unroll
            for (int t = 0; t < 9; ++t) {
                int m = n - 4 + t;
                m = (m < 0) ? (-1 - m) : ((m > 15) ? (31 - m) : m);  // compile-time
                se2 = __hfma2(k2[t], re[m % 9][c], se2);
                sg2 = __hfma2(k2[t], rg[m % 9][c], sg2);
            }
            const float2 sef = __half22float2(se2);
            const float2 sgf = __half22float2(sg2);
            const float2 ief = __half22float2(*(__half2*)&ieq[c]);
            const float2 igf = __half22float2(*(__half2*)&igq[c]);

            // point 0
            {
                float ee = __expf(-sef.x), eg = __expf(-sgf.x);
                float Re = ief.x * ee;
                float Rg = igf.x * eg;
                float Le = __builtin_amdgcn_rcpf(ee);
                float Lg = __builtin_amdgcn_rcpf(eg);
                float dr = Re - Rg, dl = Le - Lg;
                acc += dr * dr + dl * dl;
            }
            // point 1
            {
                float ee = __expf(-sef.y), eg = __expf(-sgf.y);
                float Re = ief.y * ee;
                float Rg = igf.y * eg;
                float Le = __builtin_amdgcn_rcpf(ee);
                float Lg = __builtin_amdgcn_rcpf(eg);
                float dr = Re - Rg, dl = Le - Lg;
                acc += dr * dr + dl * dl;
            }
        }
        if (n + 1 < 16) {
#pragma unroll
            for (int c = 0; c < 3; ++c) { ieq[c] = nie[c]; igq[c] = nig[c]; }
        }
    }
#undef LOADRAW
#undef CBLUR

    __shared__ float red[256];
    red[tid] = acc;
    __syncthreads();
#pragma unroll
    for (int s = 128; s > 0; s >>= 1) {
        if (tid < s) red[tid] += red[tid + s];
        __syncthreads();
    }
    if (tid == 0) atomicAdd(out, red[0] * (1.0f / (float)NEL));
}

extern "C" void kernel_launch(void* const* d_in, const int* in_sizes, int n_in,
                              void* d_out, int out_size, void* d_ws, size_t ws_size,
                              hipStream_t stream) {
    const float* Ie = (const float*)d_in[0];
    const float* Ig = (const float*)d_in[1];

    // Gaussian taps: sigma=1, radius=int(4*1+0.5)=4, double-precision normalize
    Taps tp;
    {
        double kk[9], s = 0.0;
        for (int i = 0; i < 9; ++i) { double x = (double)(i - 4); kk[i] = exp(-0.5 * x * x); s += kk[i]; }
        for (int i = 0; i < 9; ++i) tp.k[i] = (float)(kk[i] / s);
    }

    // C-axis (size 3) 9-tap symmetric blur collapsed to a 3x3 matrix
    CMat cm;
    {
        for (int c = 0; c < 3; ++c) {
            cm.w[c][0] = cm.w[c][1] = cm.w[c][2] = 0.f;
            for (int t = 0; t < 9; ++t) {
                int m = c - 4 + t;
                int mm = ((m % 6) + 6) % 6;          // symmetric reflect, period 6
                if (mm > 2) mm = 5 - mm;
                cm.w[c][mm] += tp.k[t];
            }
        }
    }

    ushort* wsS = (ushort*)d_ws;                 // fp16 blurred logs, 50.3 MB
    ushort* wsI = wsS + 2 * (size_t)NEL;         // fp16 (I+eps), 50.3 MB

    hipMemsetAsync(d_out, 0, sizeof(float), stream);  // zero the atomic target
    dim3 g1(32, 96);
    k_blur_hw<<<g1, 64, 0, stream>>>(Ie, Ig, wsS, wsI, tp);
    k_cn_loss<<<512, 256, 0, stream>>>(wsS, wsI, (float*)d_out, tp, cm);
}